// Round 20
// baseline (172.326 us; speedup 1.0000x reference)
//
#include <hip/hip_runtime.h>
#include <cstdint>

// CrossLayerAttention on MI355X (gfx950).  B=4 S=1024 H=2048 NH=16 HD=128.
// R20: = R19 + (1) attn __launch_bounds__(256,4) (VGPR 132->128, 4 blocks/CU);
//      (2) gemm_bt MODE 0 C-write via LDS scratch (16B stores, was 4B scatter).
//      prep at its measured floor (~53us) — unchanged.

typedef unsigned short u16;
typedef __bf16 bf16x8 __attribute__((ext_vector_type(8)));
typedef float  f32x4  __attribute__((ext_vector_type(4)));
typedef float  f32x16 __attribute__((ext_vector_type(16)));
typedef uint32_t u32x4 __attribute__((ext_vector_type(4)));

__device__ __forceinline__ u16 f2bf(float f) {
  uint32_t u = __builtin_bit_cast(uint32_t, f);
  u += 0x7fffu + ((u >> 16) & 1u);   // RNE; inputs finite
  return (u16)(u >> 16);
}
__device__ __forceinline__ uint32_t cvtpk(float lo, float hi) {
  uint32_t r;
  asm("v_cvt_pk_bf16_f32 %0, %1, %2" : "=v"(r) : "v"(lo), "v"(hi));
  return r;
}
__device__ __forceinline__ void gld16(const void* g, void* l) {
  __builtin_amdgcn_global_load_lds(
      (const __attribute__((address_space(1))) void*)g,
      (__attribute__((address_space(3))) void*)l, 16, 0, 0);
}

// ---------------- fused prep (R17 verbatim) ----------------
__global__ __launch_bounds__(256)
void prep_kernel(const float* __restrict__ hs, const float* __restrict__ wq,
                 const float* __restrict__ wo, const float* __restrict__ key,
                 const float* __restrict__ val,
                 u16* __restrict__ hs_o, u16* __restrict__ wq_o,
                 u16* __restrict__ wo_o, u16* __restrict__ kT,
                 u16* __restrict__ vT) {
  const int bx = blockIdx.x, tid = threadIdx.x;
  if (bx < 2048) {
    const int stride = 2048 * 256;
    for (int i = bx * 256 + tid; i < 2097152; i += stride) {   // float8 units
      const float* in; u16* out; int j;
      if (i < 1048576)      { in = hs; out = hs_o; j = i; }
      else if (i < 1572864) { in = wq; out = wq_o; j = i - 1048576; }
      else                  { in = wo; out = wo_o; j = i - 1572864; }
      float4 a = ((const float4*)in)[2 * j];
      float4 b2 = ((const float4*)in)[2 * j + 1];
      u32x4 o;
      o.x = cvtpk(a.x, a.y);  o.y = cvtpk(a.z, a.w);
      o.z = cvtpk(b2.x, b2.y); o.w = cvtpk(b2.z, b2.w);
      *(u32x4*)(out + 8 * (size_t)j) = o;
    }
    return;
  }
  __shared__ float tile[64][65];
  const bool isK = bx < 4096;
  const int idx = bx - (isK ? 2048 : 4096);
  const int R = isK ? 128 : 1024, C = isK ? 1024 : 128;
  const int nct = C >> 6;
  const int bh = idx >> 5, y = idx & 31;
  const int rt = y / nct, ct = y % nct;
  const float* src = (isK ? key : val) + (size_t)bh * 131072;
  u16* dst = (isK ? kT : vT) + (size_t)bh * 131072;
  {
    const int r = tid >> 2, cq = tid & 3;
    const float* srow = src + (size_t)(rt * 64 + r) * C + ct * 64;
    float4 v0 = *(const float4*)(srow + cq * 16 + 0);
    float4 v1 = *(const float4*)(srow + cq * 16 + 4);
    float4 v2 = *(const float4*)(srow + cq * 16 + 8);
    float4 v3 = *(const float4*)(srow + cq * 16 + 12);
    *(float4*)&tile[r][cq * 16 + 0]  = v0;
    *(float4*)&tile[r][cq * 16 + 4]  = v1;
    *(float4*)&tile[r][cq * 16 + 8]  = v2;
    *(float4*)&tile[r][cq * 16 + 12] = v3;
  }
  __syncthreads();
  {
    const int os = tid >> 2, cq = tid & 3;
    const int oc0 = cq * 16;
    u16* drow = dst + (size_t)(ct * 64 + os) * R + rt * 64 + oc0;
    u32x4 o1, o2;
    o1.x = cvtpk(tile[oc0 + 0][os],  tile[oc0 + 1][os]);
    o1.y = cvtpk(tile[oc0 + 2][os],  tile[oc0 + 3][os]);
    o1.z = cvtpk(tile[oc0 + 4][os],  tile[oc0 + 5][os]);
    o1.w = cvtpk(tile[oc0 + 6][os],  tile[oc0 + 7][os]);
    o2.x = cvtpk(tile[oc0 + 8][os],  tile[oc0 + 9][os]);
    o2.y = cvtpk(tile[oc0 + 10][os], tile[oc0 + 11][os]);
    o2.z = cvtpk(tile[oc0 + 12][os], tile[oc0 + 13][os]);
    o2.w = cvtpk(tile[oc0 + 14][os], tile[oc0 + 15][os]);
    *(u32x4*)(drow + 0) = o1;
    *(u32x4*)(drow + 8) = o2;
  }
}

// ---------------- GEMM: 256x128 tile, BK=64, 3-buf counted-vmcnt pipeline ----------------
// MODE 0: out = A@B^T + bias (fp32 out; C-write via LDS scratch, 16B stores).
// MODE 1: q-proj + fused RoPE (bf16 out; epilogue via LDS).
template<int MODE>
__global__ __launch_bounds__(512, 1)
void gemm256(const u16* __restrict__ A, const u16* __restrict__ Bm,
             const float* __restrict__ bias, const float* __restrict__ cosb,
             const float* __restrict__ sinb, void* __restrict__ Cout) {
  constexpr int K = 2048, N = 2048, NT = 32;
  __shared__ __align__(16) u16 LA[3][256 * 64];   // 3 x 32 KB
  __shared__ __align__(16) u16 LB[3][128 * 64];   // 3 x 16 KB
  const int t = threadIdx.x, lane = t & 63, w = t >> 6;
  const int row0 = blockIdx.x * 256, col0 = blockIdx.y * 128;
  const int wr = (w >> 1) * 64;
  const int g = w & 1;
  const int fr = lane & 15, fg = lane >> 4, fx = fr & 7;
  const int sb8 = ((t & 7) ^ ((t >> 3) & 7)) * 8;
  const u16* gA = A  + (size_t)(row0 + (t >> 3)) * K + sb8;
  const u16* gB = Bm + (size_t)(col0 + (t >> 3)) * K + sb8;
  const int lo8 = t * 8;

  int brow[4];
  if constexpr (MODE == 1) {
    brow[0] = g * 32 + fr;      brow[1] = g * 32 + 16 + fr;
    brow[2] = g * 32 + 64 + fr; brow[3] = g * 32 + 80 + fr;
  } else {
    brow[0] = g * 64 + fr;      brow[1] = g * 64 + 16 + fr;
    brow[2] = g * 64 + 32 + fr; brow[3] = g * 64 + 48 + fr;
  }

  f32x4 acc[4][4] = {};

  auto SA0 = [&](int kt, int buf) {
    const int k0 = kt * 64;
    gld16(gA + k0,                    &LA[buf][lo8]);
    gld16(gA + k0 + (size_t)64 * K,   &LA[buf][4096 + lo8]);
    gld16(gB + k0,                    &LB[buf][lo8]);
  };
  auto SA1 = [&](int kt, int buf) {
    const int k0 = kt * 64;
    gld16(gA + k0 + (size_t)128 * K,  &LA[buf][8192 + lo8]);
    gld16(gA + k0 + (size_t)192 * K,  &LA[buf][12288 + lo8]);
    gld16(gB + k0 + (size_t)64 * K,   &LB[buf][4096 + lo8]);
  };

  SA0(0, 0); SA1(0, 0);
  SA0(1, 1); SA1(1, 1);

  int cb = 0;
  for (int kt = 0; kt < NT; ++kt) {
    const int sbuf = cb >= 1 ? cb - 1 : cb + 2;
    if (kt < NT - 1) asm volatile("s_waitcnt vmcnt(6)" ::: "memory");
    else             asm volatile("s_waitcnt vmcnt(0)" ::: "memory");
    __builtin_amdgcn_s_barrier();
    asm volatile("" ::: "memory");

    bf16x8 af[4][2], bq0[2][2];
#pragma unroll
    for (int mi = 0; mi < 4; mi++)
#pragma unroll
      for (int ks = 0; ks < 2; ks++)
        af[mi][ks] = *(const bf16x8*)&LA[cb][(wr + mi * 16 + fr) * 64 + ((ks * 4 + fg) ^ fx) * 8];
#pragma unroll
    for (int ni = 0; ni < 2; ni++)
#pragma unroll
      for (int ks = 0; ks < 2; ks++)
        bq0[ni][ks] = *(const bf16x8*)&LB[cb][brow[ni] * 64 + ((ks * 4 + fg) ^ fx) * 8];
    if (kt + 2 < NT) SA0(kt + 2, sbuf);
    __builtin_amdgcn_s_setprio(1);
#pragma unroll
    for (int ks = 0; ks < 2; ks++)
#pragma unroll
      for (int mi = 0; mi < 4; mi++)
#pragma unroll
        for (int ni = 0; ni < 2; ni++)
          acc[mi][ni] = __builtin_amdgcn_mfma_f32_16x16x32_bf16(af[mi][ks], bq0[ni][ks], acc[mi][ni], 0, 0, 0);
    __builtin_amdgcn_s_setprio(0);
    __builtin_amdgcn_s_barrier();
    asm volatile("" ::: "memory");

    bf16x8 bq1[2][2];
#pragma unroll
    for (int ni = 0; ni < 2; ni++)
#pragma unroll
      for (int ks = 0; ks < 2; ks++)
        bq1[ni][ks] = *(const bf16x8*)&LB[cb][brow[ni + 2] * 64 + ((ks * 4 + fg) ^ fx) * 8];
    if (kt + 2 < NT) SA1(kt + 2, sbuf);
    __builtin_amdgcn_s_setprio(1);
#pragma unroll
    for (int ks = 0; ks < 2; ks++)
#pragma unroll
      for (int mi = 0; mi < 4; mi++)
#pragma unroll
        for (int ni = 0; ni < 2; ni++)
          acc[mi][ni + 2] = __builtin_amdgcn_mfma_f32_16x16x32_bf16(af[mi][ks], bq1[ni][ks], acc[mi][ni + 2], 0, 0, 0);
    __builtin_amdgcn_s_setprio(0);

    cb = cb == 2 ? 0 : cb + 1;
  }

  if constexpr (MODE == 0) {
    // C-write via LDS scratch: fp32 [256][128] mapped rows 0..191 -> LA,
    // rows 192..255 -> LB[0] (LB[1], read by trailing phase-1, untouched).
    auto srow = [&](int r) -> float* {
      return (r < 192) ? (float*)(&LA[0][0] + (size_t)r * 256)
                       : (float*)(&LB[0][0] + (size_t)(r - 192) * 256);
    };
    float bv[4];
#pragma unroll
    for (int ni = 0; ni < 4; ni++) bv[ni] = bias[col0 + brow[ni]];
    __syncthreads();
#pragma unroll
    for (int mi = 0; mi < 4; mi++)
#pragma unroll
      for (int i = 0; i < 4; i++) {
        float* sr = srow(wr + mi * 16 + fg * 4 + i);
#pragma unroll
        for (int ni = 0; ni < 4; ni++)
          sr[brow[ni]] = acc[mi][ni][i] + bv[ni];
      }
    __syncthreads();
    float* C = (float*)Cout;
#pragma unroll
    for (int p = 0; p < 16; p++) {
      int li = t + p * 512;                  // [0, 8192) 16B units
      int lr = li >> 5, seg = li & 31;
      *(float4*)(C + (size_t)(row0 + lr) * N + col0 + seg * 4)
          = *(const float4*)(srow(lr) + seg * 4);
    }
  } else {
    // rope epilogue via LDS scratch (R19, verified)
    const int h = blockIdx.y;
    const float SL2E = 0.12751743f;               // (1/sqrt(128)) * log2(e)
    float bv[4];
#pragma unroll
    for (int ni = 0; ni < 4; ni++) bv[ni] = bias[h * 128 + brow[ni]];
    u16* qout = (u16*)Cout;
    u16* sc = &LA[0][0];
#pragma unroll
    for (int mi = 0; mi < 4; mi++)
#pragma unroll
      for (int i = 0; i < 4; i++) {
        int lrow = wr + mi * 16 + fg * 4 + i;      // 0..255
        int s = (row0 + lrow) & 1023;
#pragma unroll
        for (int dp = 0; dp < 2; dp++) {
          int d = g * 32 + dp * 16 + fr;           // 0..63
          float c  = cosb[s * 128 + d] * SL2E;
          float sn = sinb[s * 128 + d] * SL2E;
          float qlo = acc[mi][dp][i] + bv[dp];
          float qhi = acc[mi][dp + 2][i] + bv[dp + 2];
          sc[lrow * 128 + d]      = f2bf(qlo * c - qhi * sn);
          sc[lrow * 128 + d + 64] = f2bf(qhi * c + qlo * sn);
        }
      }
    __syncthreads();
    const int bb = row0 >> 10;
#pragma unroll
    for (int p = 0; p < 8; p++) {
      int li = t + p * 512;                        // [0, 4096) 16B units
      int lr = li >> 4, seg = li & 15;
      int s = (row0 + lr) & 1023;
      *(u32x4*)(qout + (((size_t)(bb * 16 + h)) * 1024 + s) * 128 + seg * 8)
          = *(const u32x4*)(sc + lr * 128 + seg * 8);
    }
  }
}

// ---------------- Flash attention: KVBLK=32, 4 waves, BQ=128, 4 blocks/CU ----------------
// 512 blocks x 256 thr. qt = 7-(x>>6), bh = x&63 (R11 mapping, verified best).
__global__ __launch_bounds__(256, 4)
void attn_kernel(const u16* __restrict__ qbf, const u16* __restrict__ kTb,
                 const u16* __restrict__ vTb, u16* __restrict__ aout) {
  __shared__ __align__(16) u16 Kb[2][32 * 128];   // 2 x 8 KB
  __shared__ __align__(16) u16 Vb[2][128 * 32];   // 2 x 8 KB
  const int t = threadIdx.x, lane = t & 63, w = t >> 6;   // w in 0..3
  const int x = blockIdx.x;
  const int qt = 7 - (x >> 6);
  const int bh = x & 63;
  const int b = bh >> 4, h = bh & 15;
  const int q31 = lane & 31, hi = lane >> 5;
  const int kx7 = q31 & 7, kx3 = q31 & 3;
  const u16* kbase = kTb + (size_t)bh * 131072;   // [s][d]
  const u16* vbase = vTb + (size_t)bh * 131072;   // [d][s]

  const int kRow = t >> 4;                        // + p*16 (K: 16 slots/row)
  const int kCb  = (t & 15) ^ (kRow & 7);
  const int vRow = t >> 2;                        // + p*64 (V: 4 slots/row)
  const int vCb  = (t & 3) ^ (vRow & 3);

  const int rw0 = qt * 128 + w * 32;
  const int rowg = rw0 + q31;
  const int last = qt * 4 + 3;
  const int wlast = qt * 4 + w;                   // diag tile for this wave

  bf16x8 qf[8];
#pragma unroll
  for (int ds = 0; ds < 8; ds++)
    qf[ds] = *(const bf16x8*)&qbf[((size_t)bh * 1024 + rowg) * 128 + ds * 16 + hi * 8];

  f32x16 acc[4] = {};
  float m = -3e38f, l = 0.f;

  auto STAGE = [&](int kt, int buf) {
    const u16* ks = kbase + (size_t)(kt * 32 + kRow) * 128 + kCb * 8;
    const u16* vs = vbase + (size_t)vRow * 1024 + kt * 32 + vCb * 8;
    u16* kl = &Kb[buf][t * 8];
    u16* vl = &Vb[buf][t * 8];
#pragma unroll
    for (int p = 0; p < 2; p++) {
      gld16(ks + (size_t)p * 16 * 128, kl + p * 2048);
      gld16(vs + (size_t)p * 64 * 1024, vl + p * 2048);
    }
  };

  STAGE(0, 0);
  __syncthreads();
  for (int kt = 0; kt <= last; kt++) {
    const int cur = kt & 1;
    if (kt < last) STAGE(kt + 1, cur ^ 1);
    if (kt <= wlast) {
      // ---- QK^T (swapped): sa = S^T[kv 0..31][q], log2 domain ----
      f32x16 sa = {};
      __builtin_amdgcn_s_setprio(1);
#pragma unroll
      for (int ds = 0; ds < 8; ds++) {
        bf16x8 kf = *(const bf16x8*)&Kb[cur][q31 * 128 + (((2 * ds + hi) ^ kx7) * 8)];
        sa = __builtin_amdgcn_mfma_f32_32x32x16_bf16(kf, qf[ds], sa, 0, 0, 0);
      }
      __builtin_amdgcn_s_setprio(0);

      if (kt == wlast) {
#pragma unroll
        for (int rr = 0; rr < 16; rr++) {
          int cr = (rr & 3) + 8 * (rr >> 2) + 4 * hi;
          if (kt * 32 + cr > rowg) sa[rr] = -1e9f;
        }
      }
      float t0 = fmaxf(fmaxf(sa[0], sa[1]), sa[2]);
      float t1 = fmaxf(fmaxf(sa[3], sa[4]), sa[5]);
      float t2 = fmaxf(fmaxf(sa[6], sa[7]), sa[8]);
      float t3 = fmaxf(fmaxf(sa[9], sa[10]), sa[11]);
      float t4 = fmaxf(fmaxf(sa[12], sa[13]), sa[14]);
      float mx = fmaxf(fmaxf(fmaxf(t0, t1), t2),
                       fmaxf(fmaxf(t3, t4), sa[15]));
      mx = fmaxf(mx, __shfl_xor(mx, 32));
      if (!__all(mx - m <= 11.5f)) {              // defer-max (T13, log2 units)
        float mn = fmaxf(m, mx);
        float corr = __builtin_amdgcn_exp2f(m - mn);
        m = mn; l *= corr;
#pragma unroll
        for (int nd = 0; nd < 4; nd++)
#pragma unroll
          for (int rr = 0; rr < 16; rr++) acc[nd][rr] *= corr;
      }
#pragma unroll
      for (int rr = 0; rr < 16; rr++) sa[rr] = __builtin_amdgcn_exp2f(sa[rr] - m);
      {
        float s0 = (sa[0] + sa[1]) + (sa[2] + sa[3]);
        float s1 = (sa[4] + sa[5]) + (sa[6] + sa[7]);
        float s2 = (sa[8] + sa[9]) + (sa[10] + sa[11]);
        float s3 = (sa[12] + sa[13]) + (sa[14] + sa[15]);
        float sum = (s0 + s1) + (s2 + s3);
        sum += __shfl_xor(sum, 32);
        l += sum;
      }

      // ---- P -> bf16 A-frags via v_cvt_pk + shfl_xor(32) (T12) + PV ----
      __builtin_amdgcn_s_setprio(1);
      uint32_t wA = cvtpk(sa[0], sa[1]),   wB = cvtpk(sa[2], sa[3]);
      uint32_t wC = cvtpk(sa[4], sa[5]),   wD = cvtpk(sa[6], sa[7]);
      uint32_t wE = cvtpk(sa[8], sa[9]),   wF = cvtpk(sa[10], sa[11]);
      uint32_t wG = cvtpk(sa[12], sa[13]), wH = cvtpk(sa[14], sa[15]);
      uint32_t xA = __shfl_xor(wA, 32), xB = __shfl_xor(wB, 32);
      uint32_t xC = __shfl_xor(wC, 32), xD = __shfl_xor(wD, 32);
      uint32_t xE = __shfl_xor(wE, 32), xF = __shfl_xor(wF, 32);
      uint32_t xG = __shfl_xor(wG, 32), xH = __shfl_xor(wH, 32);
#pragma unroll
      for (int ks = 0; ks < 2; ks++) {
        u32x4 aw;
        if (ks == 0) {
          aw.x = hi ? xC : wA;  aw.y = hi ? xD : wB;
          aw.z = hi ? wC : xA;  aw.w = hi ? wD : xB;
        } else {
          aw.x = hi ? xG : wE;  aw.y = hi ? xH : wF;
          aw.z = hi ? wG : xE;  aw.w = hi ? wH : xF;
        }
        bf16x8 af = __builtin_bit_cast(bf16x8, aw);
#pragma unroll
        for (int nd = 0; nd < 4; nd++) {
          bf16x8 vf = *(const bf16x8*)&Vb[cur][(nd * 32 + q31) * 32 + (((2 * ks + hi) ^ kx3) * 8)];
          acc[nd] = __builtin_amdgcn_mfma_f32_32x32x16_bf16(af, vf, acc[nd], 0, 0, 0);
        }
      }
      __builtin_amdgcn_s_setprio(0);
    }
    __syncthreads();
  }

  // ---- epilogue ----
  float linv = 1.f / l;
#pragma unroll
  for (int rr = 0; rr < 16; rr++) {
    int cr = (rr & 3) + 8 * (rr >> 2) + 4 * hi;
    float li = __shfl(linv, cr);
    int sg = rw0 + cr;
    size_t obase = (((size_t)b * 1024 + sg) * 16 + h) * 128 + q31;
#pragma unroll
    for (int nd = 0; nd < 4; nd++)
      aout[obase + nd * 32] = f2bf(acc[nd][rr] * li);
  }
}

// ---------------- launcher ----------------
extern "C" void kernel_launch(void* const* d_in, const int* in_sizes, int n_in,
                              void* d_out, int out_size, void* d_ws, size_t ws_size,
                              hipStream_t stream) {
  const float* hs  = (const float*)d_in[0];
  const float* key = (const float*)d_in[1];
  const float* val = (const float*)d_in[2];
  // d_in[3]: attention_mask — causal, reproduced analytically
  const float* rc  = (const float*)d_in[4];
  const float* rs  = (const float*)d_in[5];
  const float* wq  = (const float*)d_in[6];
  const float* bq  = (const float*)d_in[7];
  const float* wo  = (const float*)d_in[8];
  const float* bo  = (const float*)d_in[9];
  float* out = (float*)d_out;

  char* ws = (char*)d_ws;
  u16* hs_bf = (u16*)(ws);                   // 16 MB ; reused as attn_bf
  u16* wq_bf = (u16*)(ws + 16777216);        //  8 MB
  u16* wo_bf = (u16*)(ws + 25165824);        //  8 MB
  u16* q_bf  = (u16*)(ws + 33554432);        // 16 MB
  u16* kT    = (u16*)(ws + 50331648);        // 16 MB  [bh][s][d]
  u16* vT    = (u16*)(ws + 67108864);        // 16 MB  [bh][d][s]
  u16* attn_bf = hs_bf;                      // hs_bf dead after gemm_rope

  prep_kernel<<<6144, 256, 0, stream>>>(hs, wq, wo, key, val,
                                        hs_bf, wq_bf, wo_bf, kT, vT);

  gemm256<1><<<dim3(16, 16), 512, 0, stream>>>(hs_bf, wq_bf, bq, rc, rs, q_bf);
  attn_kernel<<<512, 256, 0, stream>>>(q_bf, kT, vT, attn_bf);
  gemm256<0><<<dim3(16, 16), 512, 0, stream>>>(attn_bf, wo_bf, bo, nullptr, nullptr, out);
}

// Round 21
// 147.560 us; speedup vs baseline: 1.1678x; 1.1678x over previous
//
#include <hip/hip_runtime.h>
#include <cstdint>

// CrossLayerAttention on MI355X (gfx950).  B=4 S=1024 H=2048 NH=16 HD=128.
// R21: attn reverted to __launch_bounds__(256,3) (R20's (256,4) forced VGPR
//      64 -> spills, attn 40->75us). gemm_bt MODE 0 LDS-scratch C-write kept.
//      Otherwise identical to R19 (best passing, 146.7us).

typedef unsigned short u16;
typedef __bf16 bf16x8 __attribute__((ext_vector_type(8)));
typedef float  f32x4  __attribute__((ext_vector_type(4)));
typedef float  f32x16 __attribute__((ext_vector_type(16)));
typedef uint32_t u32x4 __attribute__((ext_vector_type(4)));

__device__ __forceinline__ u16 f2bf(float f) {
  uint32_t u = __builtin_bit_cast(uint32_t, f);
  u += 0x7fffu + ((u >> 16) & 1u);   // RNE; inputs finite
  return (u16)(u >> 16);
}
__device__ __forceinline__ uint32_t cvtpk(float lo, float hi) {
  uint32_t r;
  asm("v_cvt_pk_bf16_f32 %0, %1, %2" : "=v"(r) : "v"(lo), "v"(hi));
  return r;
}
__device__ __forceinline__ void gld16(const void* g, void* l) {
  __builtin_amdgcn_global_load_lds(
      (const __attribute__((address_space(1))) void*)g,
      (__attribute__((address_space(3))) void*)l, 16, 0, 0);
}

// ---------------- fused prep (R17 verbatim) ----------------
__global__ __launch_bounds__(256)
void prep_kernel(const float* __restrict__ hs, const float* __restrict__ wq,
                 const float* __restrict__ wo, const float* __restrict__ key,
                 const float* __restrict__ val,
                 u16* __restrict__ hs_o, u16* __restrict__ wq_o,
                 u16* __restrict__ wo_o, u16* __restrict__ kT,
                 u16* __restrict__ vT) {
  const int bx = blockIdx.x, tid = threadIdx.x;
  if (bx < 2048) {
    const int stride = 2048 * 256;
    for (int i = bx * 256 + tid; i < 2097152; i += stride) {   // float8 units
      const float* in; u16* out; int j;
      if (i < 1048576)      { in = hs; out = hs_o; j = i; }
      else if (i < 1572864) { in = wq; out = wq_o; j = i - 1048576; }
      else                  { in = wo; out = wo_o; j = i - 1572864; }
      float4 a = ((const float4*)in)[2 * j];
      float4 b2 = ((const float4*)in)[2 * j + 1];
      u32x4 o;
      o.x = cvtpk(a.x, a.y);  o.y = cvtpk(a.z, a.w);
      o.z = cvtpk(b2.x, b2.y); o.w = cvtpk(b2.z, b2.w);
      *(u32x4*)(out + 8 * (size_t)j) = o;
    }
    return;
  }
  __shared__ float tile[64][65];
  const bool isK = bx < 4096;
  const int idx = bx - (isK ? 2048 : 4096);
  const int R = isK ? 128 : 1024, C = isK ? 1024 : 128;
  const int nct = C >> 6;
  const int bh = idx >> 5, y = idx & 31;
  const int rt = y / nct, ct = y % nct;
  const float* src = (isK ? key : val) + (size_t)bh * 131072;
  u16* dst = (isK ? kT : vT) + (size_t)bh * 131072;
  {
    const int r = tid >> 2, cq = tid & 3;
    const float* srow = src + (size_t)(rt * 64 + r) * C + ct * 64;
    float4 v0 = *(const float4*)(srow + cq * 16 + 0);
    float4 v1 = *(const float4*)(srow + cq * 16 + 4);
    float4 v2 = *(const float4*)(srow + cq * 16 + 8);
    float4 v3 = *(const float4*)(srow + cq * 16 + 12);
    *(float4*)&tile[r][cq * 16 + 0]  = v0;
    *(float4*)&tile[r][cq * 16 + 4]  = v1;
    *(float4*)&tile[r][cq * 16 + 8]  = v2;
    *(float4*)&tile[r][cq * 16 + 12] = v3;
  }
  __syncthreads();
  {
    const int os = tid >> 2, cq = tid & 3;
    const int oc0 = cq * 16;
    u16* drow = dst + (size_t)(ct * 64 + os) * R + rt * 64 + oc0;
    u32x4 o1, o2;
    o1.x = cvtpk(tile[oc0 + 0][os],  tile[oc0 + 1][os]);
    o1.y = cvtpk(tile[oc0 + 2][os],  tile[oc0 + 3][os]);
    o1.z = cvtpk(tile[oc0 + 4][os],  tile[oc0 + 5][os]);
    o1.w = cvtpk(tile[oc0 + 6][os],  tile[oc0 + 7][os]);
    o2.x = cvtpk(tile[oc0 + 8][os],  tile[oc0 + 9][os]);
    o2.y = cvtpk(tile[oc0 + 10][os], tile[oc0 + 11][os]);
    o2.z = cvtpk(tile[oc0 + 12][os], tile[oc0 + 13][os]);
    o2.w = cvtpk(tile[oc0 + 14][os], tile[oc0 + 15][os]);
    *(u32x4*)(drow + 0) = o1;
    *(u32x4*)(drow + 8) = o2;
  }
}

// ---------------- GEMM: 256x128 tile, BK=64, 3-buf counted-vmcnt pipeline ----------------
// MODE 0: out = A@B^T + bias (fp32 out; C-write via LDS scratch, 16B stores).
// MODE 1: q-proj + fused RoPE (bf16 out; epilogue via LDS).
template<int MODE>
__global__ __launch_bounds__(512, 1)
void gemm256(const u16* __restrict__ A, const u16* __restrict__ Bm,
             const float* __restrict__ bias, const float* __restrict__ cosb,
             const float* __restrict__ sinb, void* __restrict__ Cout) {
  constexpr int K = 2048, N = 2048, NT = 32;
  __shared__ __align__(16) u16 LA[3][256 * 64];   // 3 x 32 KB
  __shared__ __align__(16) u16 LB[3][128 * 64];   // 3 x 16 KB
  const int t = threadIdx.x, lane = t & 63, w = t >> 6;
  const int row0 = blockIdx.x * 256, col0 = blockIdx.y * 128;
  const int wr = (w >> 1) * 64;
  const int g = w & 1;
  const int fr = lane & 15, fg = lane >> 4, fx = fr & 7;
  const int sb8 = ((t & 7) ^ ((t >> 3) & 7)) * 8;
  const u16* gA = A  + (size_t)(row0 + (t >> 3)) * K + sb8;
  const u16* gB = Bm + (size_t)(col0 + (t >> 3)) * K + sb8;
  const int lo8 = t * 8;

  int brow[4];
  if constexpr (MODE == 1) {
    brow[0] = g * 32 + fr;      brow[1] = g * 32 + 16 + fr;
    brow[2] = g * 32 + 64 + fr; brow[3] = g * 32 + 80 + fr;
  } else {
    brow[0] = g * 64 + fr;      brow[1] = g * 64 + 16 + fr;
    brow[2] = g * 64 + 32 + fr; brow[3] = g * 64 + 48 + fr;
  }

  f32x4 acc[4][4] = {};

  auto SA0 = [&](int kt, int buf) {
    const int k0 = kt * 64;
    gld16(gA + k0,                    &LA[buf][lo8]);
    gld16(gA + k0 + (size_t)64 * K,   &LA[buf][4096 + lo8]);
    gld16(gB + k0,                    &LB[buf][lo8]);
  };
  auto SA1 = [&](int kt, int buf) {
    const int k0 = kt * 64;
    gld16(gA + k0 + (size_t)128 * K,  &LA[buf][8192 + lo8]);
    gld16(gA + k0 + (size_t)192 * K,  &LA[buf][12288 + lo8]);
    gld16(gB + k0 + (size_t)64 * K,   &LB[buf][4096 + lo8]);
  };

  SA0(0, 0); SA1(0, 0);
  SA0(1, 1); SA1(1, 1);

  int cb = 0;
  for (int kt = 0; kt < NT; ++kt) {
    const int sbuf = cb >= 1 ? cb - 1 : cb + 2;
    if (kt < NT - 1) asm volatile("s_waitcnt vmcnt(6)" ::: "memory");
    else             asm volatile("s_waitcnt vmcnt(0)" ::: "memory");
    __builtin_amdgcn_s_barrier();
    asm volatile("" ::: "memory");

    bf16x8 af[4][2], bq0[2][2];
#pragma unroll
    for (int mi = 0; mi < 4; mi++)
#pragma unroll
      for (int ks = 0; ks < 2; ks++)
        af[mi][ks] = *(const bf16x8*)&LA[cb][(wr + mi * 16 + fr) * 64 + ((ks * 4 + fg) ^ fx) * 8];
#pragma unroll
    for (int ni = 0; ni < 2; ni++)
#pragma unroll
      for (int ks = 0; ks < 2; ks++)
        bq0[ni][ks] = *(const bf16x8*)&LB[cb][brow[ni] * 64 + ((ks * 4 + fg) ^ fx) * 8];
    if (kt + 2 < NT) SA0(kt + 2, sbuf);
    __builtin_amdgcn_s_setprio(1);
#pragma unroll
    for (int ks = 0; ks < 2; ks++)
#pragma unroll
      for (int mi = 0; mi < 4; mi++)
#pragma unroll
        for (int ni = 0; ni < 2; ni++)
          acc[mi][ni] = __builtin_amdgcn_mfma_f32_16x16x32_bf16(af[mi][ks], bq0[ni][ks], acc[mi][ni], 0, 0, 0);
    __builtin_amdgcn_s_setprio(0);
    __builtin_amdgcn_s_barrier();
    asm volatile("" ::: "memory");

    bf16x8 bq1[2][2];
#pragma unroll
    for (int ni = 0; ni < 2; ni++)
#pragma unroll
      for (int ks = 0; ks < 2; ks++)
        bq1[ni][ks] = *(const bf16x8*)&LB[cb][brow[ni + 2] * 64 + ((ks * 4 + fg) ^ fx) * 8];
    if (kt + 2 < NT) SA1(kt + 2, sbuf);
    __builtin_amdgcn_s_setprio(1);
#pragma unroll
    for (int ks = 0; ks < 2; ks++)
#pragma unroll
      for (int mi = 0; mi < 4; mi++)
#pragma unroll
        for (int ni = 0; ni < 2; ni++)
          acc[mi][ni + 2] = __builtin_amdgcn_mfma_f32_16x16x32_bf16(af[mi][ks], bq1[ni][ks], acc[mi][ni + 2], 0, 0, 0);
    __builtin_amdgcn_s_setprio(0);

    cb = cb == 2 ? 0 : cb + 1;
  }

  if constexpr (MODE == 0) {
    // C-write via LDS scratch: fp32 [256][128]; rows 0..191 -> LA,
    // rows 192..255 -> LB[0].
    auto srow = [&](int r) -> float* {
      return (r < 192) ? (float*)(&LA[0][0] + (size_t)r * 256)
                       : (float*)(&LB[0][0] + (size_t)(r - 192) * 256);
    };
    float bv[4];
#pragma unroll
    for (int ni = 0; ni < 4; ni++) bv[ni] = bias[col0 + brow[ni]];
    __syncthreads();
#pragma unroll
    for (int mi = 0; mi < 4; mi++)
#pragma unroll
      for (int i = 0; i < 4; i++) {
        float* sr = srow(wr + mi * 16 + fg * 4 + i);
#pragma unroll
        for (int ni = 0; ni < 4; ni++)
          sr[brow[ni]] = acc[mi][ni][i] + bv[ni];
      }
    __syncthreads();
    float* C = (float*)Cout;
#pragma unroll
    for (int p = 0; p < 16; p++) {
      int li = t + p * 512;                  // [0, 8192) 16B units
      int lr = li >> 5, seg = li & 31;
      *(float4*)(C + (size_t)(row0 + lr) * N + col0 + seg * 4)
          = *(const float4*)(srow(lr) + seg * 4);
    }
  } else {
    // rope epilogue via LDS scratch (R19, verified)
    const int h = blockIdx.y;
    const float SL2E = 0.12751743f;               // (1/sqrt(128)) * log2(e)
    float bv[4];
#pragma unroll
    for (int ni = 0; ni < 4; ni++) bv[ni] = bias[h * 128 + brow[ni]];
    u16* qout = (u16*)Cout;
    u16* sc = &LA[0][0];
#pragma unroll
    for (int mi = 0; mi < 4; mi++)
#pragma unroll
      for (int i = 0; i < 4; i++) {
        int lrow = wr + mi * 16 + fg * 4 + i;      // 0..255
        int s = (row0 + lrow) & 1023;
#pragma unroll
        for (int dp = 0; dp < 2; dp++) {
          int d = g * 32 + dp * 16 + fr;           // 0..63
          float c  = cosb[s * 128 + d] * SL2E;
          float sn = sinb[s * 128 + d] * SL2E;
          float qlo = acc[mi][dp][i] + bv[dp];
          float qhi = acc[mi][dp + 2][i] + bv[dp + 2];
          sc[lrow * 128 + d]      = f2bf(qlo * c - qhi * sn);
          sc[lrow * 128 + d + 64] = f2bf(qhi * c + qlo * sn);
        }
      }
    __syncthreads();
    const int bb = row0 >> 10;
#pragma unroll
    for (int p = 0; p < 8; p++) {
      int li = t + p * 512;                        // [0, 4096) 16B units
      int lr = li >> 4, seg = li & 15;
      int s = (row0 + lr) & 1023;
      *(u32x4*)(qout + (((size_t)(bb * 16 + h)) * 1024 + s) * 128 + seg * 8)
          = *(const u32x4*)(sc + lr * 128 + seg * 8);
    }
  }
}

// ---------------- Flash attention: KVBLK=32, 4 waves, BQ=128, 3 blocks/CU ----------------
// 512 blocks x 256 thr. qt = 7-(x>>6), bh = x&63 (R11 mapping, verified best).
__global__ __launch_bounds__(256, 3)
void attn_kernel(const u16* __restrict__ qbf, const u16* __restrict__ kTb,
                 const u16* __restrict__ vTb, u16* __restrict__ aout) {
  __shared__ __align__(16) u16 Kb[2][32 * 128];   // 2 x 8 KB
  __shared__ __align__(16) u16 Vb[2][128 * 32];   // 2 x 8 KB
  const int t = threadIdx.x, lane = t & 63, w = t >> 6;   // w in 0..3
  const int x = blockIdx.x;
  const int qt = 7 - (x >> 6);
  const int bh = x & 63;
  const int b = bh >> 4, h = bh & 15;
  const int q31 = lane & 31, hi = lane >> 5;
  const int kx7 = q31 & 7, kx3 = q31 & 3;
  const u16* kbase = kTb + (size_t)bh * 131072;   // [s][d]
  const u16* vbase = vTb + (size_t)bh * 131072;   // [d][s]

  const int kRow = t >> 4;                        // + p*16 (K: 16 slots/row)
  const int kCb  = (t & 15) ^ (kRow & 7);
  const int vRow = t >> 2;                        // + p*64 (V: 4 slots/row)
  const int vCb  = (t & 3) ^ (vRow & 3);

  const int rw0 = qt * 128 + w * 32;
  const int rowg = rw0 + q31;
  const int last = qt * 4 + 3;
  const int wlast = qt * 4 + w;                   // diag tile for this wave

  bf16x8 qf[8];
#pragma unroll
  for (int ds = 0; ds < 8; ds++)
    qf[ds] = *(const bf16x8*)&qbf[((size_t)bh * 1024 + rowg) * 128 + ds * 16 + hi * 8];

  f32x16 acc[4] = {};
  float m = -3e38f, l = 0.f;

  auto STAGE = [&](int kt, int buf) {
    const u16* ks = kbase + (size_t)(kt * 32 + kRow) * 128 + kCb * 8;
    const u16* vs = vbase + (size_t)vRow * 1024 + kt * 32 + vCb * 8;
    u16* kl = &Kb[buf][t * 8];
    u16* vl = &Vb[buf][t * 8];
#pragma unroll
    for (int p = 0; p < 2; p++) {
      gld16(ks + (size_t)p * 16 * 128, kl + p * 2048);
      gld16(vs + (size_t)p * 64 * 1024, vl + p * 2048);
    }
  };

  STAGE(0, 0);
  __syncthreads();
  for (int kt = 0; kt <= last; kt++) {
    const int cur = kt & 1;
    if (kt < last) STAGE(kt + 1, cur ^ 1);
    if (kt <= wlast) {
      // ---- QK^T (swapped): sa = S^T[kv 0..31][q], log2 domain ----
      f32x16 sa = {};
      __builtin_amdgcn_s_setprio(1);
#pragma unroll
      for (int ds = 0; ds < 8; ds++) {
        bf16x8 kf = *(const bf16x8*)&Kb[cur][q31 * 128 + (((2 * ds + hi) ^ kx7) * 8)];
        sa = __builtin_amdgcn_mfma_f32_32x32x16_bf16(kf, qf[ds], sa, 0, 0, 0);
      }
      __builtin_amdgcn_s_setprio(0);

      if (kt == wlast) {
#pragma unroll
        for (int rr = 0; rr < 16; rr++) {
          int cr = (rr & 3) + 8 * (rr >> 2) + 4 * hi;
          if (kt * 32 + cr > rowg) sa[rr] = -1e9f;
        }
      }
      float t0 = fmaxf(fmaxf(sa[0], sa[1]), sa[2]);
      float t1 = fmaxf(fmaxf(sa[3], sa[4]), sa[5]);
      float t2 = fmaxf(fmaxf(sa[6], sa[7]), sa[8]);
      float t3 = fmaxf(fmaxf(sa[9], sa[10]), sa[11]);
      float t4 = fmaxf(fmaxf(sa[12], sa[13]), sa[14]);
      float mx = fmaxf(fmaxf(fmaxf(t0, t1), t2),
                       fmaxf(fmaxf(t3, t4), sa[15]));
      mx = fmaxf(mx, __shfl_xor(mx, 32));
      if (!__all(mx - m <= 11.5f)) {              // defer-max (T13, log2 units)
        float mn = fmaxf(m, mx);
        float corr = __builtin_amdgcn_exp2f(m - mn);
        m = mn; l *= corr;
#pragma unroll
        for (int nd = 0; nd < 4; nd++)
#pragma unroll
          for (int rr = 0; rr < 16; rr++) acc[nd][rr] *= corr;
      }
#pragma unroll
      for (int rr = 0; rr < 16; rr++) sa[rr] = __builtin_amdgcn_exp2f(sa[rr] - m);
      {
        float s0 = (sa[0] + sa[1]) + (sa[2] + sa[3]);
        float s1 = (sa[4] + sa[5]) + (sa[6] + sa[7]);
        float s2 = (sa[8] + sa[9]) + (sa[10] + sa[11]);
        float s3 = (sa[12] + sa[13]) + (sa[14] + sa[15]);
        float sum = (s0 + s1) + (s2 + s3);
        sum += __shfl_xor(sum, 32);
        l += sum;
      }

      // ---- P -> bf16 A-frags via v_cvt_pk + shfl_xor(32) (T12) + PV ----
      __builtin_amdgcn_s_setprio(1);
      uint32_t wA = cvtpk(sa[0], sa[1]),   wB = cvtpk(sa[2], sa[3]);
      uint32_t wC = cvtpk(sa[4], sa[5]),   wD = cvtpk(sa[6], sa[7]);
      uint32_t wE = cvtpk(sa[8], sa[9]),   wF = cvtpk(sa[10], sa[11]);
      uint32_t wG = cvtpk(sa[12], sa[13]), wH = cvtpk(sa[14], sa[15]);
      uint32_t xA = __shfl_xor(wA, 32), xB = __shfl_xor(wB, 32);
      uint32_t xC = __shfl_xor(wC, 32), xD = __shfl_xor(wD, 32);
      uint32_t xE = __shfl_xor(wE, 32), xF = __shfl_xor(wF, 32);
      uint32_t xG = __shfl_xor(wG, 32), xH = __shfl_xor(wH, 32);
#pragma unroll
      for (int ks = 0; ks < 2; ks++) {
        u32x4 aw;
        if (ks == 0) {
          aw.x = hi ? xC : wA;  aw.y = hi ? xD : wB;
          aw.z = hi ? wC : xA;  aw.w = hi ? wD : xB;
        } else {
          aw.x = hi ? xG : wE;  aw.y = hi ? xH : wF;
          aw.z = hi ? wG : xE;  aw.w = hi ? wH : xF;
        }
        bf16x8 af = __builtin_bit_cast(bf16x8, aw);
#pragma unroll
        for (int nd = 0; nd < 4; nd++) {
          bf16x8 vf = *(const bf16x8*)&Vb[cur][(nd * 32 + q31) * 32 + (((2 * ks + hi) ^ kx3) * 8)];
          acc[nd] = __builtin_amdgcn_mfma_f32_32x32x16_bf16(af, vf, acc[nd], 0, 0, 0);
        }
      }
      __builtin_amdgcn_s_setprio(0);
    }
    __syncthreads();
  }

  // ---- epilogue ----
  float linv = 1.f / l;
#pragma unroll
  for (int rr = 0; rr < 16; rr++) {
    int cr = (rr & 3) + 8 * (rr >> 2) + 4 * hi;
    float li = __shfl(linv, cr);
    int sg = rw0 + cr;
    size_t obase = (((size_t)b * 1024 + sg) * 16 + h) * 128 + q31;
#pragma unroll
    for (int nd = 0; nd < 4; nd++)
      aout[obase + nd * 32] = f2bf(acc[nd][rr] * li);
  }
}

// ---------------- launcher ----------------
extern "C" void kernel_launch(void* const* d_in, const int* in_sizes, int n_in,
                              void* d_out, int out_size, void* d_ws, size_t ws_size,
                              hipStream_t stream) {
  const float* hs  = (const float*)d_in[0];
  const float* key = (const float*)d_in[1];
  const float* val = (const float*)d_in[2];
  // d_in[3]: attention_mask — causal, reproduced analytically
  const float* rc  = (const float*)d_in[4];
  const float* rs  = (const float*)d_in[5];
  const float* wq  = (const float*)d_in[6];
  const float* bq  = (const float*)d_in[7];
  const float* wo  = (const float*)d_in[8];
  const float* bo  = (const float*)d_in[9];
  float* out = (float*)d_out;

  char* ws = (char*)d_ws;
  u16* hs_bf = (u16*)(ws);                   // 16 MB ; reused as attn_bf
  u16* wq_bf = (u16*)(ws + 16777216);        //  8 MB
  u16* wo_bf = (u16*)(ws + 25165824);        //  8 MB
  u16* q_bf  = (u16*)(ws + 33554432);        // 16 MB
  u16* kT    = (u16*)(ws + 50331648);        // 16 MB  [bh][s][d]
  u16* vT    = (u16*)(ws + 67108864);        // 16 MB  [bh][d][s]
  u16* attn_bf = hs_bf;                      // hs_bf dead after gemm_rope

  prep_kernel<<<6144, 256, 0, stream>>>(hs, wq, wo, key, val,
                                        hs_bf, wq_bf, wo_bf, kT, vT);

  gemm256<1><<<dim3(16, 16), 512, 0, stream>>>(hs_bf, wq_bf, bq, rc, rs, q_bf);
  attn_kernel<<<512, 256, 0, stream>>>(q_bf, kT, vT, attn_bf);
  gemm256<0><<<dim3(16, 16), 512, 0, stream>>>(attn_bf, wo_bf, bo, nullptr, nullptr, out);
}

// Round 22
// 146.517 us; speedup vs baseline: 1.1762x; 1.0071x over previous
//
#include <hip/hip_runtime.h>
#include <cstdint>

// CrossLayerAttention on MI355X (gfx950).  B=4 S=1024 H=2048 NH=16 HD=128.
// R22: = R21 with gemm256's mid-iteration barrier removed (single barrier per
//      K-tile; 3-buf rotation makes it correctness-safe — reads hit cb, writes
//      hit (cb+2)%3, waves stay within one iteration of each other).

typedef unsigned short u16;
typedef __bf16 bf16x8 __attribute__((ext_vector_type(8)));
typedef float  f32x4  __attribute__((ext_vector_type(4)));
typedef float  f32x16 __attribute__((ext_vector_type(16)));
typedef uint32_t u32x4 __attribute__((ext_vector_type(4)));

__device__ __forceinline__ u16 f2bf(float f) {
  uint32_t u = __builtin_bit_cast(uint32_t, f);
  u += 0x7fffu + ((u >> 16) & 1u);   // RNE; inputs finite
  return (u16)(u >> 16);
}
__device__ __forceinline__ uint32_t cvtpk(float lo, float hi) {
  uint32_t r;
  asm("v_cvt_pk_bf16_f32 %0, %1, %2" : "=v"(r) : "v"(lo), "v"(hi));
  return r;
}
__device__ __forceinline__ void gld16(const void* g, void* l) {
  __builtin_amdgcn_global_load_lds(
      (const __attribute__((address_space(1))) void*)g,
      (__attribute__((address_space(3))) void*)l, 16, 0, 0);
}

// ---------------- fused prep (R17 verbatim) ----------------
__global__ __launch_bounds__(256)
void prep_kernel(const float* __restrict__ hs, const float* __restrict__ wq,
                 const float* __restrict__ wo, const float* __restrict__ key,
                 const float* __restrict__ val,
                 u16* __restrict__ hs_o, u16* __restrict__ wq_o,
                 u16* __restrict__ wo_o, u16* __restrict__ kT,
                 u16* __restrict__ vT) {
  const int bx = blockIdx.x, tid = threadIdx.x;
  if (bx < 2048) {
    const int stride = 2048 * 256;
    for (int i = bx * 256 + tid; i < 2097152; i += stride) {   // float8 units
      const float* in; u16* out; int j;
      if (i < 1048576)      { in = hs; out = hs_o; j = i; }
      else if (i < 1572864) { in = wq; out = wq_o; j = i - 1048576; }
      else                  { in = wo; out = wo_o; j = i - 1572864; }
      float4 a = ((const float4*)in)[2 * j];
      float4 b2 = ((const float4*)in)[2 * j + 1];
      u32x4 o;
      o.x = cvtpk(a.x, a.y);  o.y = cvtpk(a.z, a.w);
      o.z = cvtpk(b2.x, b2.y); o.w = cvtpk(b2.z, b2.w);
      *(u32x4*)(out + 8 * (size_t)j) = o;
    }
    return;
  }
  __shared__ float tile[64][65];
  const bool isK = bx < 4096;
  const int idx = bx - (isK ? 2048 : 4096);
  const int R = isK ? 128 : 1024, C = isK ? 1024 : 128;
  const int nct = C >> 6;
  const int bh = idx >> 5, y = idx & 31;
  const int rt = y / nct, ct = y % nct;
  const float* src = (isK ? key : val) + (size_t)bh * 131072;
  u16* dst = (isK ? kT : vT) + (size_t)bh * 131072;
  {
    const int r = tid >> 2, cq = tid & 3;
    const float* srow = src + (size_t)(rt * 64 + r) * C + ct * 64;
    float4 v0 = *(const float4*)(srow + cq * 16 + 0);
    float4 v1 = *(const float4*)(srow + cq * 16 + 4);
    float4 v2 = *(const float4*)(srow + cq * 16 + 8);
    float4 v3 = *(const float4*)(srow + cq * 16 + 12);
    *(float4*)&tile[r][cq * 16 + 0]  = v0;
    *(float4*)&tile[r][cq * 16 + 4]  = v1;
    *(float4*)&tile[r][cq * 16 + 8]  = v2;
    *(float4*)&tile[r][cq * 16 + 12] = v3;
  }
  __syncthreads();
  {
    const int os = tid >> 2, cq = tid & 3;
    const int oc0 = cq * 16;
    u16* drow = dst + (size_t)(ct * 64 + os) * R + rt * 64 + oc0;
    u32x4 o1, o2;
    o1.x = cvtpk(tile[oc0 + 0][os],  tile[oc0 + 1][os]);
    o1.y = cvtpk(tile[oc0 + 2][os],  tile[oc0 + 3][os]);
    o1.z = cvtpk(tile[oc0 + 4][os],  tile[oc0 + 5][os]);
    o1.w = cvtpk(tile[oc0 + 6][os],  tile[oc0 + 7][os]);
    o2.x = cvtpk(tile[oc0 + 8][os],  tile[oc0 + 9][os]);
    o2.y = cvtpk(tile[oc0 + 10][os], tile[oc0 + 11][os]);
    o2.z = cvtpk(tile[oc0 + 12][os], tile[oc0 + 13][os]);
    o2.w = cvtpk(tile[oc0 + 14][os], tile[oc0 + 15][os]);
    *(u32x4*)(drow + 0) = o1;
    *(u32x4*)(drow + 8) = o2;
  }
}

// ---------------- GEMM: 256x128 tile, BK=64, 3-buf counted-vmcnt, 1 barrier/iter ----------------
// MODE 0: out = A@B^T + bias (fp32 out; C-write via LDS scratch).
// MODE 1: q-proj + fused RoPE (bf16 out; epilogue via LDS).
template<int MODE>
__global__ __launch_bounds__(512, 1)
void gemm256(const u16* __restrict__ A, const u16* __restrict__ Bm,
             const float* __restrict__ bias, const float* __restrict__ cosb,
             const float* __restrict__ sinb, void* __restrict__ Cout) {
  constexpr int K = 2048, N = 2048, NT = 32;
  __shared__ __align__(16) u16 LA[3][256 * 64];   // 3 x 32 KB
  __shared__ __align__(16) u16 LB[3][128 * 64];   // 3 x 16 KB
  const int t = threadIdx.x, lane = t & 63, w = t >> 6;
  const int row0 = blockIdx.x * 256, col0 = blockIdx.y * 128;
  const int wr = (w >> 1) * 64;
  const int g = w & 1;
  const int fr = lane & 15, fg = lane >> 4, fx = fr & 7;
  const int sb8 = ((t & 7) ^ ((t >> 3) & 7)) * 8;
  const u16* gA = A  + (size_t)(row0 + (t >> 3)) * K + sb8;
  const u16* gB = Bm + (size_t)(col0 + (t >> 3)) * K + sb8;
  const int lo8 = t * 8;

  int brow[4];
  if constexpr (MODE == 1) {
    brow[0] = g * 32 + fr;      brow[1] = g * 32 + 16 + fr;
    brow[2] = g * 32 + 64 + fr; brow[3] = g * 32 + 80 + fr;
  } else {
    brow[0] = g * 64 + fr;      brow[1] = g * 64 + 16 + fr;
    brow[2] = g * 64 + 32 + fr; brow[3] = g * 64 + 48 + fr;
  }

  f32x4 acc[4][4] = {};

  auto SA0 = [&](int kt, int buf) {
    const int k0 = kt * 64;
    gld16(gA + k0,                    &LA[buf][lo8]);
    gld16(gA + k0 + (size_t)64 * K,   &LA[buf][4096 + lo8]);
    gld16(gB + k0,                    &LB[buf][lo8]);
  };
  auto SA1 = [&](int kt, int buf) {
    const int k0 = kt * 64;
    gld16(gA + k0 + (size_t)128 * K,  &LA[buf][8192 + lo8]);
    gld16(gA + k0 + (size_t)192 * K,  &LA[buf][12288 + lo8]);
    gld16(gB + k0 + (size_t)64 * K,   &LB[buf][4096 + lo8]);
  };

  SA0(0, 0); SA1(0, 0);
  SA0(1, 1); SA1(1, 1);

  int cb = 0;
  for (int kt = 0; kt < NT; ++kt) {
    const int sbuf = cb >= 1 ? cb - 1 : cb + 2;   // (cb+2)%3
    if (kt < NT - 1) asm volatile("s_waitcnt vmcnt(6)" ::: "memory");
    else             asm volatile("s_waitcnt vmcnt(0)" ::: "memory");
    __builtin_amdgcn_s_barrier();
    asm volatile("" ::: "memory");

    bf16x8 af[4][2], bq0[2][2], bq1[2][2];
#pragma unroll
    for (int mi = 0; mi < 4; mi++)
#pragma unroll
      for (int ks = 0; ks < 2; ks++)
        af[mi][ks] = *(const bf16x8*)&LA[cb][(wr + mi * 16 + fr) * 64 + ((ks * 4 + fg) ^ fx) * 8];
#pragma unroll
    for (int ni = 0; ni < 2; ni++)
#pragma unroll
      for (int ks = 0; ks < 2; ks++) {
        bq0[ni][ks] = *(const bf16x8*)&LB[cb][brow[ni] * 64 + ((ks * 4 + fg) ^ fx) * 8];
        bq1[ni][ks] = *(const bf16x8*)&LB[cb][brow[ni + 2] * 64 + ((ks * 4 + fg) ^ fx) * 8];
      }
    if (kt + 2 < NT) { SA0(kt + 2, sbuf); SA1(kt + 2, sbuf); }
    __builtin_amdgcn_s_setprio(1);
#pragma unroll
    for (int ks = 0; ks < 2; ks++)
#pragma unroll
      for (int mi = 0; mi < 4; mi++)
#pragma unroll
        for (int ni = 0; ni < 2; ni++) {
          acc[mi][ni]     = __builtin_amdgcn_mfma_f32_16x16x32_bf16(af[mi][ks], bq0[ni][ks], acc[mi][ni], 0, 0, 0);
          acc[mi][ni + 2] = __builtin_amdgcn_mfma_f32_16x16x32_bf16(af[mi][ks], bq1[ni][ks], acc[mi][ni + 2], 0, 0, 0);
        }
    __builtin_amdgcn_s_setprio(0);

    cb = cb == 2 ? 0 : cb + 1;
  }

  if constexpr (MODE == 0) {
    // C-write via LDS scratch: fp32 [256][128]; rows 0..191 -> LA,
    // rows 192..255 -> LB[0].
    auto srow = [&](int r) -> float* {
      return (r < 192) ? (float*)(&LA[0][0] + (size_t)r * 256)
                       : (float*)(&LB[0][0] + (size_t)(r - 192) * 256);
    };
    float bv[4];
#pragma unroll
    for (int ni = 0; ni < 4; ni++) bv[ni] = bias[col0 + brow[ni]];
    __syncthreads();
#pragma unroll
    for (int mi = 0; mi < 4; mi++)
#pragma unroll
      for (int i = 0; i < 4; i++) {
        float* sr = srow(wr + mi * 16 + fg * 4 + i);
#pragma unroll
        for (int ni = 0; ni < 4; ni++)
          sr[brow[ni]] = acc[mi][ni][i] + bv[ni];
      }
    __syncthreads();
    float* C = (float*)Cout;
#pragma unroll
    for (int p = 0; p < 16; p++) {
      int li = t + p * 512;                  // [0, 8192) 16B units
      int lr = li >> 5, seg = li & 31;
      *(float4*)(C + (size_t)(row0 + lr) * N + col0 + seg * 4)
          = *(const float4*)(srow(lr) + seg * 4);
    }
  } else {
    // rope epilogue via LDS scratch (R19, verified)
    const int h = blockIdx.y;
    const float SL2E = 0.12751743f;               // (1/sqrt(128)) * log2(e)
    float bv[4];
#pragma unroll
    for (int ni = 0; ni < 4; ni++) bv[ni] = bias[h * 128 + brow[ni]];
    u16* qout = (u16*)Cout;
    u16* sc = &LA[0][0];
#pragma unroll
    for (int mi = 0; mi < 4; mi++)
#pragma unroll
      for (int i = 0; i < 4; i++) {
        int lrow = wr + mi * 16 + fg * 4 + i;      // 0..255
        int s = (row0 + lrow) & 1023;
#pragma unroll
        for (int dp = 0; dp < 2; dp++) {
          int d = g * 32 + dp * 16 + fr;           // 0..63
          float c  = cosb[s * 128 + d] * SL2E;
          float sn = sinb[s * 128 + d] * SL2E;
          float qlo = acc[mi][dp][i] + bv[dp];
          float qhi = acc[mi][dp + 2][i] + bv[dp + 2];
          sc[lrow * 128 + d]      = f2bf(qlo * c - qhi * sn);
          sc[lrow * 128 + d + 64] = f2bf(qhi * c + qlo * sn);
        }
      }
    __syncthreads();
    const int bb = row0 >> 10;
#pragma unroll
    for (int p = 0; p < 8; p++) {
      int li = t + p * 512;                        // [0, 4096) 16B units
      int lr = li >> 4, seg = li & 15;
      int s = (row0 + lr) & 1023;
      *(u32x4*)(qout + (((size_t)(bb * 16 + h)) * 1024 + s) * 128 + seg * 8)
          = *(const u32x4*)(sc + lr * 128 + seg * 8);
    }
  }
}

// ---------------- Flash attention: KVBLK=32, 4 waves, BQ=128, (256,3) ----------------
// 512 blocks x 256 thr. qt = 7-(x>>6), bh = x&63 (R11 mapping, verified best).
__global__ __launch_bounds__(256, 3)
void attn_kernel(const u16* __restrict__ qbf, const u16* __restrict__ kTb,
                 const u16* __restrict__ vTb, u16* __restrict__ aout) {
  __shared__ __align__(16) u16 Kb[2][32 * 128];   // 2 x 8 KB
  __shared__ __align__(16) u16 Vb[2][128 * 32];   // 2 x 8 KB
  const int t = threadIdx.x, lane = t & 63, w = t >> 6;   // w in 0..3
  const int x = blockIdx.x;
  const int qt = 7 - (x >> 6);
  const int bh = x & 63;
  const int b = bh >> 4, h = bh & 15;
  const int q31 = lane & 31, hi = lane >> 5;
  const int kx7 = q31 & 7, kx3 = q31 & 3;
  const u16* kbase = kTb + (size_t)bh * 131072;   // [s][d]
  const u16* vbase = vTb + (size_t)bh * 131072;   // [d][s]

  const int kRow = t >> 4;                        // + p*16 (K: 16 slots/row)
  const int kCb  = (t & 15) ^ (kRow & 7);
  const int vRow = t >> 2;                        // + p*64 (V: 4 slots/row)
  const int vCb  = (t & 3) ^ (vRow & 3);

  const int rw0 = qt * 128 + w * 32;
  const int rowg = rw0 + q31;
  const int last = qt * 4 + 3;
  const int wlast = qt * 4 + w;                   // diag tile for this wave

  bf16x8 qf[8];
#pragma unroll
  for (int ds = 0; ds < 8; ds++)
    qf[ds] = *(const bf16x8*)&qbf[((size_t)bh * 1024 + rowg) * 128 + ds * 16 + hi * 8];

  f32x16 acc[4] = {};
  float m = -3e38f, l = 0.f;

  auto STAGE = [&](int kt, int buf) {
    const u16* ks = kbase + (size_t)(kt * 32 + kRow) * 128 + kCb * 8;
    const u16* vs = vbase + (size_t)vRow * 1024 + kt * 32 + vCb * 8;
    u16* kl = &Kb[buf][t * 8];
    u16* vl = &Vb[buf][t * 8];
#pragma unroll
    for (int p = 0; p < 2; p++) {
      gld16(ks + (size_t)p * 16 * 128, kl + p * 2048);
      gld16(vs + (size_t)p * 64 * 1024, vl + p * 2048);
    }
  };

  STAGE(0, 0);
  __syncthreads();
  for (int kt = 0; kt <= last; kt++) {
    const int cur = kt & 1;
    if (kt < last) STAGE(kt + 1, cur ^ 1);
    if (kt <= wlast) {
      // ---- QK^T (swapped): sa = S^T[kv 0..31][q], log2 domain ----
      f32x16 sa = {};
      __builtin_amdgcn_s_setprio(1);
#pragma unroll
      for (int ds = 0; ds < 8; ds++) {
        bf16x8 kf = *(const bf16x8*)&Kb[cur][q31 * 128 + (((2 * ds + hi) ^ kx7) * 8)];
        sa = __builtin_amdgcn_mfma_f32_32x32x16_bf16(kf, qf[ds], sa, 0, 0, 0);
      }
      __builtin_amdgcn_s_setprio(0);

      if (kt == wlast) {
#pragma unroll
        for (int rr = 0; rr < 16; rr++) {
          int cr = (rr & 3) + 8 * (rr >> 2) + 4 * hi;
          if (kt * 32 + cr > rowg) sa[rr] = -1e9f;
        }
      }
      float t0 = fmaxf(fmaxf(sa[0], sa[1]), sa[2]);
      float t1 = fmaxf(fmaxf(sa[3], sa[4]), sa[5]);
      float t2 = fmaxf(fmaxf(sa[6], sa[7]), sa[8]);
      float t3 = fmaxf(fmaxf(sa[9], sa[10]), sa[11]);
      float t4 = fmaxf(fmaxf(sa[12], sa[13]), sa[14]);
      float mx = fmaxf(fmaxf(fmaxf(t0, t1), t2),
                       fmaxf(fmaxf(t3, t4), sa[15]));
      mx = fmaxf(mx, __shfl_xor(mx, 32));
      if (!__all(mx - m <= 11.5f)) {              // defer-max (T13, log2 units)
        float mn = fmaxf(m, mx);
        float corr = __builtin_amdgcn_exp2f(m - mn);
        m = mn; l *= corr;
#pragma unroll
        for (int nd = 0; nd < 4; nd++)
#pragma unroll
          for (int rr = 0; rr < 16; rr++) acc[nd][rr] *= corr;
      }
#pragma unroll
      for (int rr = 0; rr < 16; rr++) sa[rr] = __builtin_amdgcn_exp2f(sa[rr] - m);
      {
        float s0 = (sa[0] + sa[1]) + (sa[2] + sa[3]);
        float s1 = (sa[4] + sa[5]) + (sa[6] + sa[7]);
        float s2 = (sa[8] + sa[9]) + (sa[10] + sa[11]);
        float s3 = (sa[12] + sa[13]) + (sa[14] + sa[15]);
        float sum = (s0 + s1) + (s2 + s3);
        sum += __shfl_xor(sum, 32);
        l += sum;
      }

      // ---- P -> bf16 A-frags via v_cvt_pk + shfl_xor(32) (T12) + PV ----
      __builtin_amdgcn_s_setprio(1);
      uint32_t wA = cvtpk(sa[0], sa[1]),   wB = cvtpk(sa[2], sa[3]);
      uint32_t wC = cvtpk(sa[4], sa[5]),   wD = cvtpk(sa[6], sa[7]);
      uint32_t wE = cvtpk(sa[8], sa[9]),   wF = cvtpk(sa[10], sa[11]);
      uint32_t wG = cvtpk(sa[12], sa[13]), wH = cvtpk(sa[14], sa[15]);
      uint32_t xA = __shfl_xor(wA, 32), xB = __shfl_xor(wB, 32);
      uint32_t xC = __shfl_xor(wC, 32), xD = __shfl_xor(wD, 32);
      uint32_t xE = __shfl_xor(wE, 32), xF = __shfl_xor(wF, 32);
      uint32_t xG = __shfl_xor(wG, 32), xH = __shfl_xor(wH, 32);
#pragma unroll
      for (int ks = 0; ks < 2; ks++) {
        u32x4 aw;
        if (ks == 0) {
          aw.x = hi ? xC : wA;  aw.y = hi ? xD : wB;
          aw.z = hi ? wC : xA;  aw.w = hi ? wD : xB;
        } else {
          aw.x = hi ? xG : wE;  aw.y = hi ? xH : wF;
          aw.z = hi ? wG : xE;  aw.w = hi ? wH : xF;
        }
        bf16x8 af = __builtin_bit_cast(bf16x8, aw);
#pragma unroll
        for (int nd = 0; nd < 4; nd++) {
          bf16x8 vf = *(const bf16x8*)&Vb[cur][(nd * 32 + q31) * 32 + (((2 * ks + hi) ^ kx3) * 8)];
          acc[nd] = __builtin_amdgcn_mfma_f32_32x32x16_bf16(af, vf, acc[nd], 0, 0, 0);
        }
      }
      __builtin_amdgcn_s_setprio(0);
    }
    __syncthreads();
  }

  // ---- epilogue ----
  float linv = 1.f / l;
#pragma unroll
  for (int rr = 0; rr < 16; rr++) {
    int cr = (rr & 3) + 8 * (rr >> 2) + 4 * hi;
    float li = __shfl(linv, cr);
    int sg = rw0 + cr;
    size_t obase = (((size_t)b * 1024 + sg) * 16 + h) * 128 + q31;
#pragma unroll
    for (int nd = 0; nd < 4; nd++)
      aout[obase + nd * 32] = f2bf(acc[nd][rr] * li);
  }
}

// ---------------- launcher ----------------
extern "C" void kernel_launch(void* const* d_in, const int* in_sizes, int n_in,
                              void* d_out, int out_size, void* d_ws, size_t ws_size,
                              hipStream_t stream) {
  const float* hs  = (const float*)d_in[0];
  const float* key = (const float*)d_in[1];
  const float* val = (const float*)d_in[2];
  // d_in[3]: attention_mask — causal, reproduced analytically
  const float* rc  = (const float*)d_in[4];
  const float* rs  = (const float*)d_in[5];
  const float* wq  = (const float*)d_in[6];
  const float* bq  = (const float*)d_in[7];
  const float* wo  = (const float*)d_in[8];
  const float* bo  = (const float*)d_in[9];
  float* out = (float*)d_out;

  char* ws = (char*)d_ws;
  u16* hs_bf = (u16*)(ws);                   // 16 MB ; reused as attn_bf
  u16* wq_bf = (u16*)(ws + 16777216);        //  8 MB
  u16* wo_bf = (u16*)(ws + 25165824);        //  8 MB
  u16* q_bf  = (u16*)(ws + 33554432);        // 16 MB
  u16* kT    = (u16*)(ws + 50331648);        // 16 MB  [bh][s][d]
  u16* vT    = (u16*)(ws + 67108864);        // 16 MB  [bh][d][s]
  u16* attn_bf = hs_bf;                      // hs_bf dead after gemm_rope

  prep_kernel<<<6144, 256, 0, stream>>>(hs, wq, wo, key, val,
                                        hs_bf, wq_bf, wo_bf, kT, vT);

  gemm256<1><<<dim3(16, 16), 512, 0, stream>>>(hs_bf, wq_bf, bq, rc, rs, q_bf);
  attn_kernel<<<512, 256, 0, stream>>>(q_bf, kT, vT, attn_bf);
  gemm256<0><<<dim3(16, 16), 512, 0, stream>>>(attn_bf, wo_bf, bo, nullptr, nullptr, out);
}

// Round 23
// 145.938 us; speedup vs baseline: 1.1808x; 1.0040x over previous
//
#include <hip/hip_runtime.h>
#include <cstdint>

// CrossLayerAttention on MI355X (gfx950).  B=4 S=1024 H=2048 NH=16 HD=128.
// R23: prep = 4096 blocks; cvt work (2 float8 units/thread) fused into the
//      transpose blocks' load-latency shadow (8 loads in flight/thread).
//      gemm256 (R22, 1 barrier/iter) and attn (R15 KVBLK=32) unchanged.

typedef unsigned short u16;
typedef __bf16 bf16x8 __attribute__((ext_vector_type(8)));
typedef float  f32x4  __attribute__((ext_vector_type(4)));
typedef float  f32x16 __attribute__((ext_vector_type(16)));
typedef uint32_t u32x4 __attribute__((ext_vector_type(4)));

__device__ __forceinline__ u16 f2bf(float f) {
  uint32_t u = __builtin_bit_cast(uint32_t, f);
  u += 0x7fffu + ((u >> 16) & 1u);   // RNE; inputs finite
  return (u16)(u >> 16);
}
__device__ __forceinline__ uint32_t cvtpk(float lo, float hi) {
  uint32_t r;
  asm("v_cvt_pk_bf16_f32 %0, %1, %2" : "=v"(r) : "v"(lo), "v"(hi));
  return r;
}
__device__ __forceinline__ void gld16(const void* g, void* l) {
  __builtin_amdgcn_global_load_lds(
      (const __attribute__((address_space(1))) void*)g,
      (__attribute__((address_space(3))) void*)l, 16, 0, 0);
}

// ---------------- fused prep: transpose + cvt-in-shadow ----------------
// 4096 blocks. Block bx: transpose tile (K if bx<2048 else V) AND 512 float8
// cvt units [bx*512, bx*512+512) of hs|wq|wo. cvt loads issue after the
// transpose loads and complete under the transpose's LDS/store phase.
__global__ __launch_bounds__(256)
void prep_kernel(const float* __restrict__ hs, const float* __restrict__ wq,
                 const float* __restrict__ wo, const float* __restrict__ key,
                 const float* __restrict__ val,
                 u16* __restrict__ hs_o, u16* __restrict__ wq_o,
                 u16* __restrict__ wo_o, u16* __restrict__ kT,
                 u16* __restrict__ vT) {
  __shared__ float tile[64][65];
  const int bx = blockIdx.x, tid = threadIdx.x;
  const bool isK = bx < 2048;
  const int idx = isK ? bx : bx - 2048;
  const int R = isK ? 128 : 1024, C = isK ? 1024 : 128;
  const int nct = C >> 6;
  const int bh = idx >> 5, y = idx & 31;
  const int rt = y / nct, ct = y % nct;
  const float* src = (isK ? key : val) + (size_t)bh * 131072;
  u16* dst = (isK ? kT : vT) + (size_t)bh * 131072;
  const int r = tid >> 2, cq = tid & 3;

  // --- issue transpose loads (4 float4) ---
  const float* srow = src + (size_t)(rt * 64 + r) * C + ct * 64;
  float4 v0 = *(const float4*)(srow + cq * 16 + 0);
  float4 v1 = *(const float4*)(srow + cq * 16 + 4);
  float4 v2 = *(const float4*)(srow + cq * 16 + 8);
  float4 v3 = *(const float4*)(srow + cq * 16 + 12);

  // --- cvt work in the shadow: 2 float8 units/thread ---
  {
    const int u0 = bx * 512 + tid;              // [0, 2097152)
    const int u1 = u0 + 256;
#pragma unroll
    for (int q = 0; q < 2; q++) {
      int i = q == 0 ? u0 : u1;
      const float* in; u16* out; int j;
      if (i < 1048576)      { in = hs; out = hs_o; j = i; }
      else if (i < 1572864) { in = wq; out = wq_o; j = i - 1048576; }
      else                  { in = wo; out = wo_o; j = i - 1572864; }
      float4 a = ((const float4*)in)[2 * j];
      float4 b2 = ((const float4*)in)[2 * j + 1];
      u32x4 o;
      o.x = cvtpk(a.x, a.y);  o.y = cvtpk(a.z, a.w);
      o.z = cvtpk(b2.x, b2.y); o.w = cvtpk(b2.z, b2.w);
      *(u32x4*)(out + 8 * (size_t)j) = o;
    }
  }

  // --- transpose: LDS write, sync, packed transposed store ---
  *(float4*)&tile[r][cq * 16 + 0]  = v0;
  *(float4*)&tile[r][cq * 16 + 4]  = v1;
  *(float4*)&tile[r][cq * 16 + 8]  = v2;
  *(float4*)&tile[r][cq * 16 + 12] = v3;
  __syncthreads();
  {
    const int oc0 = cq * 16;
    u16* drow = dst + (size_t)(ct * 64 + r) * R + rt * 64 + oc0;
    u32x4 o1, o2;
    o1.x = cvtpk(tile[oc0 + 0][r],  tile[oc0 + 1][r]);
    o1.y = cvtpk(tile[oc0 + 2][r],  tile[oc0 + 3][r]);
    o1.z = cvtpk(tile[oc0 + 4][r],  tile[oc0 + 5][r]);
    o1.w = cvtpk(tile[oc0 + 6][r],  tile[oc0 + 7][r]);
    o2.x = cvtpk(tile[oc0 + 8][r],  tile[oc0 + 9][r]);
    o2.y = cvtpk(tile[oc0 + 10][r], tile[oc0 + 11][r]);
    o2.z = cvtpk(tile[oc0 + 12][r], tile[oc0 + 13][r]);
    o2.w = cvtpk(tile[oc0 + 14][r], tile[oc0 + 15][r]);
    *(u32x4*)(drow + 0) = o1;
    *(u32x4*)(drow + 8) = o2;
  }
}

// ---------------- GEMM: 256x128 tile, BK=64, 3-buf counted-vmcnt, 1 barrier/iter ----------------
// MODE 0: out = A@B^T + bias (fp32 out; C-write via LDS scratch).
// MODE 1: q-proj + fused RoPE (bf16 out; epilogue via LDS).
template<int MODE>
__global__ __launch_bounds__(512, 1)
void gemm256(const u16* __restrict__ A, const u16* __restrict__ Bm,
             const float* __restrict__ bias, const float* __restrict__ cosb,
             const float* __restrict__ sinb, void* __restrict__ Cout) {
  constexpr int K = 2048, N = 2048, NT = 32;
  __shared__ __align__(16) u16 LA[3][256 * 64];   // 3 x 32 KB
  __shared__ __align__(16) u16 LB[3][128 * 64];   // 3 x 16 KB
  const int t = threadIdx.x, lane = t & 63, w = t >> 6;
  const int row0 = blockIdx.x * 256, col0 = blockIdx.y * 128;
  const int wr = (w >> 1) * 64;
  const int g = w & 1;
  const int fr = lane & 15, fg = lane >> 4, fx = fr & 7;
  const int sb8 = ((t & 7) ^ ((t >> 3) & 7)) * 8;
  const u16* gA = A  + (size_t)(row0 + (t >> 3)) * K + sb8;
  const u16* gB = Bm + (size_t)(col0 + (t >> 3)) * K + sb8;
  const int lo8 = t * 8;

  int brow[4];
  if constexpr (MODE == 1) {
    brow[0] = g * 32 + fr;      brow[1] = g * 32 + 16 + fr;
    brow[2] = g * 32 + 64 + fr; brow[3] = g * 32 + 80 + fr;
  } else {
    brow[0] = g * 64 + fr;      brow[1] = g * 64 + 16 + fr;
    brow[2] = g * 64 + 32 + fr; brow[3] = g * 64 + 48 + fr;
  }

  f32x4 acc[4][4] = {};

  auto SA0 = [&](int kt, int buf) {
    const int k0 = kt * 64;
    gld16(gA + k0,                    &LA[buf][lo8]);
    gld16(gA + k0 + (size_t)64 * K,   &LA[buf][4096 + lo8]);
    gld16(gB + k0,                    &LB[buf][lo8]);
  };
  auto SA1 = [&](int kt, int buf) {
    const int k0 = kt * 64;
    gld16(gA + k0 + (size_t)128 * K,  &LA[buf][8192 + lo8]);
    gld16(gA + k0 + (size_t)192 * K,  &LA[buf][12288 + lo8]);
    gld16(gB + k0 + (size_t)64 * K,   &LB[buf][4096 + lo8]);
  };

  SA0(0, 0); SA1(0, 0);
  SA0(1, 1); SA1(1, 1);

  int cb = 0;
  for (int kt = 0; kt < NT; ++kt) {
    const int sbuf = cb >= 1 ? cb - 1 : cb + 2;   // (cb+2)%3
    if (kt < NT - 1) asm volatile("s_waitcnt vmcnt(6)" ::: "memory");
    else             asm volatile("s_waitcnt vmcnt(0)" ::: "memory");
    __builtin_amdgcn_s_barrier();
    asm volatile("" ::: "memory");

    bf16x8 af[4][2], bq0[2][2], bq1[2][2];
#pragma unroll
    for (int mi = 0; mi < 4; mi++)
#pragma unroll
      for (int ks = 0; ks < 2; ks++)
        af[mi][ks] = *(const bf16x8*)&LA[cb][(wr + mi * 16 + fr) * 64 + ((ks * 4 + fg) ^ fx) * 8];
#pragma unroll
    for (int ni = 0; ni < 2; ni++)
#pragma unroll
      for (int ks = 0; ks < 2; ks++) {
        bq0[ni][ks] = *(const bf16x8*)&LB[cb][brow[ni] * 64 + ((ks * 4 + fg) ^ fx) * 8];
        bq1[ni][ks] = *(const bf16x8*)&LB[cb][brow[ni + 2] * 64 + ((ks * 4 + fg) ^ fx) * 8];
      }
    if (kt + 2 < NT) { SA0(kt + 2, sbuf); SA1(kt + 2, sbuf); }
    __builtin_amdgcn_s_setprio(1);
#pragma unroll
    for (int ks = 0; ks < 2; ks++)
#pragma unroll
      for (int mi = 0; mi < 4; mi++)
#pragma unroll
        for (int ni = 0; ni < 2; ni++) {
          acc[mi][ni]     = __builtin_amdgcn_mfma_f32_16x16x32_bf16(af[mi][ks], bq0[ni][ks], acc[mi][ni], 0, 0, 0);
          acc[mi][ni + 2] = __builtin_amdgcn_mfma_f32_16x16x32_bf16(af[mi][ks], bq1[ni][ks], acc[mi][ni + 2], 0, 0, 0);
        }
    __builtin_amdgcn_s_setprio(0);

    cb = cb == 2 ? 0 : cb + 1;
  }

  if constexpr (MODE == 0) {
    auto srow = [&](int r) -> float* {
      return (r < 192) ? (float*)(&LA[0][0] + (size_t)r * 256)
                       : (float*)(&LB[0][0] + (size_t)(r - 192) * 256);
    };
    float bv[4];
#pragma unroll
    for (int ni = 0; ni < 4; ni++) bv[ni] = bias[col0 + brow[ni]];
    __syncthreads();
#pragma unroll
    for (int mi = 0; mi < 4; mi++)
#pragma unroll
      for (int i = 0; i < 4; i++) {
        float* sr = srow(wr + mi * 16 + fg * 4 + i);
#pragma unroll
        for (int ni = 0; ni < 4; ni++)
          sr[brow[ni]] = acc[mi][ni][i] + bv[ni];
      }
    __syncthreads();
    float* C = (float*)Cout;
#pragma unroll
    for (int p = 0; p < 16; p++) {
      int li = t + p * 512;                  // [0, 8192) 16B units
      int lr = li >> 5, seg = li & 31;
      *(float4*)(C + (size_t)(row0 + lr) * N + col0 + seg * 4)
          = *(const float4*)(srow(lr) + seg * 4);
    }
  } else {
    const int h = blockIdx.y;
    const float SL2E = 0.12751743f;               // (1/sqrt(128)) * log2(e)
    float bv[4];
#pragma unroll
    for (int ni = 0; ni < 4; ni++) bv[ni] = bias[h * 128 + brow[ni]];
    u16* qout = (u16*)Cout;
    u16* sc = &LA[0][0];
#pragma unroll
    for (int mi = 0; mi < 4; mi++)
#pragma unroll
      for (int i = 0; i < 4; i++) {
        int lrow = wr + mi * 16 + fg * 4 + i;      // 0..255
        int s = (row0 + lrow) & 1023;
#pragma unroll
        for (int dp = 0; dp < 2; dp++) {
          int d = g * 32 + dp * 16 + fr;           // 0..63
          float c  = cosb[s * 128 + d] * SL2E;
          float sn = sinb[s * 128 + d] * SL2E;
          float qlo = acc[mi][dp][i] + bv[dp];
          float qhi = acc[mi][dp + 2][i] + bv[dp + 2];
          sc[lrow * 128 + d]      = f2bf(qlo * c - qhi * sn);
          sc[lrow * 128 + d + 64] = f2bf(qhi * c + qlo * sn);
        }
      }
    __syncthreads();
    const int bb = row0 >> 10;
#pragma unroll
    for (int p = 0; p < 8; p++) {
      int li = t + p * 512;                        // [0, 4096) 16B units
      int lr = li >> 4, seg = li & 15;
      int s = (row0 + lr) & 1023;
      *(u32x4*)(qout + (((size_t)(bb * 16 + h)) * 1024 + s) * 128 + seg * 8)
          = *(const u32x4*)(sc + lr * 128 + seg * 8);
    }
  }
}

// ---------------- Flash attention: KVBLK=32, 4 waves, BQ=128, (256,3) ----------------
// 512 blocks x 256 thr. qt = 7-(x>>6), bh = x&63 (R11 mapping, verified best).
__global__ __launch_bounds__(256, 3)
void attn_kernel(const u16* __restrict__ qbf, const u16* __restrict__ kTb,
                 const u16* __restrict__ vTb, u16* __restrict__ aout) {
  __shared__ __align__(16) u16 Kb[2][32 * 128];   // 2 x 8 KB
  __shared__ __align__(16) u16 Vb[2][128 * 32];   // 2 x 8 KB
  const int t = threadIdx.x, lane = t & 63, w = t >> 6;   // w in 0..3
  const int x = blockIdx.x;
  const int qt = 7 - (x >> 6);
  const int bh = x & 63;
  const int b = bh >> 4, h = bh & 15;
  const int q31 = lane & 31, hi = lane >> 5;
  const int kx7 = q31 & 7, kx3 = q31 & 3;
  const u16* kbase = kTb + (size_t)bh * 131072;   // [s][d]
  const u16* vbase = vTb + (size_t)bh * 131072;   // [d][s]

  const int kRow = t >> 4;                        // + p*16 (K: 16 slots/row)
  const int kCb  = (t & 15) ^ (kRow & 7);
  const int vRow = t >> 2;                        // + p*64 (V: 4 slots/row)
  const int vCb  = (t & 3) ^ (vRow & 3);

  const int rw0 = qt * 128 + w * 32;
  const int rowg = rw0 + q31;
  const int last = qt * 4 + 3;
  const int wlast = qt * 4 + w;                   // diag tile for this wave

  bf16x8 qf[8];
#pragma unroll
  for (int ds = 0; ds < 8; ds++)
    qf[ds] = *(const bf16x8*)&qbf[((size_t)bh * 1024 + rowg) * 128 + ds * 16 + hi * 8];

  f32x16 acc[4] = {};
  float m = -3e38f, l = 0.f;

  auto STAGE = [&](int kt, int buf) {
    const u16* ks = kbase + (size_t)(kt * 32 + kRow) * 128 + kCb * 8;
    const u16* vs = vbase + (size_t)vRow * 1024 + kt * 32 + vCb * 8;
    u16* kl = &Kb[buf][t * 8];
    u16* vl = &Vb[buf][t * 8];
#pragma unroll
    for (int p = 0; p < 2; p++) {
      gld16(ks + (size_t)p * 16 * 128, kl + p * 2048);
      gld16(vs + (size_t)p * 64 * 1024, vl + p * 2048);
    }
  };

  STAGE(0, 0);
  __syncthreads();
  for (int kt = 0; kt <= last; kt++) {
    const int cur = kt & 1;
    if (kt < last) STAGE(kt + 1, cur ^ 1);
    if (kt <= wlast) {
      // ---- QK^T (swapped): sa = S^T[kv 0..31][q], log2 domain ----
      f32x16 sa = {};
      __builtin_amdgcn_s_setprio(1);
#pragma unroll
      for (int ds = 0; ds < 8; ds++) {
        bf16x8 kf = *(const bf16x8*)&Kb[cur][q31 * 128 + (((2 * ds + hi) ^ kx7) * 8)];
        sa = __builtin_amdgcn_mfma_f32_32x32x16_bf16(kf, qf[ds], sa, 0, 0, 0);
      }
      __builtin_amdgcn_s_setprio(0);

      if (kt == wlast) {
#pragma unroll
        for (int rr = 0; rr < 16; rr++) {
          int cr = (rr & 3) + 8 * (rr >> 2) + 4 * hi;
          if (kt * 32 + cr > rowg) sa[rr] = -1e9f;
        }
      }
      float t0 = fmaxf(fmaxf(sa[0], sa[1]), sa[2]);
      float t1 = fmaxf(fmaxf(sa[3], sa[4]), sa[5]);
      float t2 = fmaxf(fmaxf(sa[6], sa[7]), sa[8]);
      float t3 = fmaxf(fmaxf(sa[9], sa[10]), sa[11]);
      float t4 = fmaxf(fmaxf(sa[12], sa[13]), sa[14]);
      float mx = fmaxf(fmaxf(fmaxf(t0, t1), t2),
                       fmaxf(fmaxf(t3, t4), sa[15]));
      mx = fmaxf(mx, __shfl_xor(mx, 32));
      if (!__all(mx - m <= 11.5f)) {              // defer-max (T13, log2 units)
        float mn = fmaxf(m, mx);
        float corr = __builtin_amdgcn_exp2f(m - mn);
        m = mn; l *= corr;
#pragma unroll
        for (int nd = 0; nd < 4; nd++)
#pragma unroll
          for (int rr = 0; rr < 16; rr++) acc[nd][rr] *= corr;
      }
#pragma unroll
      for (int rr = 0; rr < 16; rr++) sa[rr] = __builtin_amdgcn_exp2f(sa[rr] - m);
      {
        float s0 = (sa[0] + sa[1]) + (sa[2] + sa[3]);
        float s1 = (sa[4] + sa[5]) + (sa[6] + sa[7]);
        float s2 = (sa[8] + sa[9]) + (sa[10] + sa[11]);
        float s3 = (sa[12] + sa[13]) + (sa[14] + sa[15]);
        float sum = (s0 + s1) + (s2 + s3);
        sum += __shfl_xor(sum, 32);
        l += sum;
      }

      // ---- P -> bf16 A-frags via v_cvt_pk + shfl_xor(32) (T12) + PV ----
      __builtin_amdgcn_s_setprio(1);
      uint32_t wA = cvtpk(sa[0], sa[1]),   wB = cvtpk(sa[2], sa[3]);
      uint32_t wC = cvtpk(sa[4], sa[5]),   wD = cvtpk(sa[6], sa[7]);
      uint32_t wE = cvtpk(sa[8], sa[9]),   wF = cvtpk(sa[10], sa[11]);
      uint32_t wG = cvtpk(sa[12], sa[13]), wH = cvtpk(sa[14], sa[15]);
      uint32_t xA = __shfl_xor(wA, 32), xB = __shfl_xor(wB, 32);
      uint32_t xC = __shfl_xor(wC, 32), xD = __shfl_xor(wD, 32);
      uint32_t xE = __shfl_xor(wE, 32), xF = __shfl_xor(wF, 32);
      uint32_t xG = __shfl_xor(wG, 32), xH = __shfl_xor(wH, 32);
#pragma unroll
      for (int ks = 0; ks < 2; ks++) {
        u32x4 aw;
        if (ks == 0) {
          aw.x = hi ? xC : wA;  aw.y = hi ? xD : wB;
          aw.z = hi ? wC : xA;  aw.w = hi ? wD : xB;
        } else {
          aw.x = hi ? xG : wE;  aw.y = hi ? xH : wF;
          aw.z = hi ? wG : xE;  aw.w = hi ? wH : xF;
        }
        bf16x8 af = __builtin_bit_cast(bf16x8, aw);
#pragma unroll
        for (int nd = 0; nd < 4; nd++) {
          bf16x8 vf = *(const bf16x8*)&Vb[cur][(nd * 32 + q31) * 32 + (((2 * ks + hi) ^ kx3) * 8)];
          acc[nd] = __builtin_amdgcn_mfma_f32_32x32x16_bf16(af, vf, acc[nd], 0, 0, 0);
        }
      }
      __builtin_amdgcn_s_setprio(0);
    }
    __syncthreads();
  }

  // ---- epilogue ----
  float linv = 1.f / l;
#pragma unroll
  for (int rr = 0; rr < 16; rr++) {
    int cr = (rr & 3) + 8 * (rr >> 2) + 4 * hi;
    float li = __shfl(linv, cr);
    int sg = rw0 + cr;
    size_t obase = (((size_t)b * 1024 + sg) * 16 + h) * 128 + q31;
#pragma unroll
    for (int nd = 0; nd < 4; nd++)
      aout[obase + nd * 32] = f2bf(acc[nd][rr] * li);
  }
}

// ---------------- launcher ----------------
extern "C" void kernel_launch(void* const* d_in, const int* in_sizes, int n_in,
                              void* d_out, int out_size, void* d_ws, size_t ws_size,
                              hipStream_t stream) {
  const float* hs  = (const float*)d_in[0];
  const float* key = (const float*)d_in[1];
  const float* val = (const float*)d_in[2];
  // d_in[3]: attention_mask — causal, reproduced analytically
  const float* rc  = (const float*)d_in[4];
  const float* rs  = (const float*)d_in[5];
  const float* wq  = (const float*)d_in[6];
  const float* bq  = (const float*)d_in[7];
  const float* wo  = (const float*)d_in[8];
  const float* bo  = (const float*)d_in[9];
  float* out = (float*)d_out;

  char* ws = (char*)d_ws;
  u16* hs_bf = (u16*)(ws);                   // 16 MB ; reused as attn_bf
  u16* wq_bf = (u16*)(ws + 16777216);        //  8 MB
  u16* wo_bf = (u16*)(ws + 25165824);        //  8 MB
  u16* q_bf  = (u16*)(ws + 33554432);        // 16 MB
  u16* kT    = (u16*)(ws + 50331648);        // 16 MB  [bh][s][d]
  u16* vT    = (u16*)(ws + 67108864);        // 16 MB  [bh][d][s]
  u16* attn_bf = hs_bf;                      // hs_bf dead after gemm_rope

  prep_kernel<<<4096, 256, 0, stream>>>(hs, wq, wo, key, val,
                                        hs_bf, wq_bf, wo_bf, kT, vT);

  gemm256<1><<<dim3(16, 16), 512, 0, stream>>>(hs_bf, wq_bf, bq, rc, rs, q_bf);
  attn_kernel<<<512, 256, 0, stream>>>(q_bf, kT, vT, attn_bf);
  gemm256<0><<<dim3(16, 16), 512, 0, stream>>>(attn_bf, wo_bf, bo, nullptr, nullptr, out);
}